// Round 1
// baseline (119.618 us; speedup 1.0000x reference)
//
#include <hip/hip_runtime.h>
#include <hip/hip_bf16.h>

// MultiHeadAttention (additive/Bahdanau): B=2, Q=K=256, HIDDEN=1024, 8 heads x 128
// Phase 0: hq' = (query@W_q)*2log2e, hk' = (keys@W_k)*2log2e   (fp32, to d_ws)
// Phase 1: logits[b,h,q,k] = S_h + sum_d (-2*Va_d)/(2^(hq'+hk')+1) - penalty  (to d_out weights region)
// Phase 2: softmax rows in place -> weights; PV -> ctx
//
// tanh(x) = 1 - 2/(e^{2x}+1); with a = 2*log2e*x: e^{2x} = 2^a. Handles +-inf saturation correctly.

#define TANH_SCALE 2.88539008177792681472f   // 2*log2(e)
#define LOG2E      1.44269504088896340736f

// ---------------- Phase 0: fp32 GEMM, C = scale * A[512,1024] @ W[1024,1024] ----------------
__global__ __launch_bounds__(256) void gemm2_f32(
    const float* __restrict__ query, const float* __restrict__ keys,
    const float* __restrict__ Wq, const float* __restrict__ Wk,
    float* __restrict__ hq, float* __restrict__ hk)
{
  const float* A = blockIdx.z ? keys : query;
  const float* W = blockIdx.z ? Wk : Wq;
  float* out     = blockIdx.z ? hk : hq;

  __shared__ __align__(16) float As[16 * 68];  // [k][m], stride 68 (pad: conflict-free, 16B-aligned rows)
  __shared__ __align__(16) float Ws[16 * 64];  // [k][n]

  const int tid = threadIdx.x;
  const int tx = tid & 15, ty = tid >> 4;
  const int m0 = blockIdx.y * 64, n0 = blockIdx.x * 64;

  // staging coords: A tile 64m x 16k; W tile 16k x 64n
  const int ak = tid & 15, am = tid >> 4;   // + i*16 on m
  const int wn = tid & 63, wk = tid >> 6;   // + i*4  on k

  float ar[4], wr[4];
#pragma unroll
  for (int i = 0; i < 4; ++i) ar[i] = A[(m0 + am + i * 16) * 1024 + ak];
#pragma unroll
  for (int i = 0; i < 4; ++i) wr[i] = W[(wk + i * 4) * 1024 + n0 + wn];

  float acc[4][4] = {};

  for (int kk = 0; kk < 1024; kk += 16) {
    __syncthreads();
#pragma unroll
    for (int i = 0; i < 4; ++i) As[ak * 68 + am + i * 16] = ar[i];
#pragma unroll
    for (int i = 0; i < 4; ++i) Ws[(wk + i * 4) * 64 + wn] = wr[i];
    __syncthreads();

    if (kk + 16 < 1024) {  // prefetch next tile into registers (hides HBM/L2 latency under FMAs)
#pragma unroll
      for (int i = 0; i < 4; ++i) ar[i] = A[(m0 + am + i * 16) * 1024 + kk + 16 + ak];
#pragma unroll
      for (int i = 0; i < 4; ++i) wr[i] = W[(kk + 16 + wk + i * 4) * 1024 + n0 + wn];
    }

#pragma unroll
    for (int k = 0; k < 16; ++k) {
      float4 af = *(const float4*)&As[k * 68 + ty * 4];
      float4 wf = *(const float4*)&Ws[k * 64 + tx * 4];
      float a[4] = {af.x, af.y, af.z, af.w};
      float w[4] = {wf.x, wf.y, wf.z, wf.w};
#pragma unroll
      for (int i = 0; i < 4; ++i)
#pragma unroll
        for (int j = 0; j < 4; ++j) acc[i][j] += a[i] * w[j];
    }
  }

#pragma unroll
  for (int i = 0; i < 4; ++i) {
    float4 o;
    o.x = acc[i][0] * TANH_SCALE; o.y = acc[i][1] * TANH_SCALE;
    o.z = acc[i][2] * TANH_SCALE; o.w = acc[i][3] * TANH_SCALE;
    *(float4*)&out[(m0 + ty * 4 + i) * 1024 + n0 + tx * 4] = o;
  }
}

// ---------------- Phase 1: logits ----------------
// grid: x = k-tile (8, TK=32), y = q-tile (32, TQ=8), z = b
__global__ __launch_bounds__(256) void logits_kernel(
    const float* __restrict__ hq, const float* __restrict__ hk,
    const float* __restrict__ Va, const int* __restrict__ mask,
    float* __restrict__ logits /* [B,8,Q,K] */)
{
  __shared__ float hk_s[32 * 129];   // stride 129: bank = (k+d)%32, conflict-free
  __shared__ float hq_s[8 * 129];
  __shared__ float vam2_s[1024];     // -2*Va
  __shared__ float Ssum[8];          // per-head sum(Va)

  const int tid = threadIdx.x;
  const int b = blockIdx.z;
  const int q0 = blockIdx.y * 8, k0 = blockIdx.x * 32;

  for (int i = tid; i < 1024; i += 256) vam2_s[i] = -2.0f * Va[i];
  __syncthreads();
  if (tid < 8) {
    float s = 0.f;
    for (int d = 0; d < 128; ++d) s += vam2_s[tid * 128 + d];
    Ssum[tid] = -0.5f * s;   // = sum(Va) over head
  }

  const int kl = tid & 31;   // key within tile
  const int qs = tid >> 5;   // query within tile (0..7)
  const float pen = 99.0f * (1.0f - (float)mask[b * 256 + k0 + kl]);

  float pf_hq[4], pf_hk[16];
  // prefetch chunk 0
#pragma unroll
  for (int i = 0; i < 4; ++i) {
    int idx = tid + i * 256; int r = idx >> 7, d = idx & 127;
    pf_hq[i] = hq[(b * 256 + q0 + r) * 1024 + d];
  }
#pragma unroll
  for (int i = 0; i < 16; ++i) {
    int idx = tid + i * 256; int r = idx >> 7, d = idx & 127;
    pf_hk[i] = hk[(b * 256 + k0 + r) * 1024 + d];
  }

  for (int ch = 0; ch < 8; ++ch) {   // one head (128 d) per chunk
    __syncthreads();
#pragma unroll
    for (int i = 0; i < 4; ++i) {
      int idx = tid + i * 256; hq_s[(idx >> 7) * 129 + (idx & 127)] = pf_hq[i];
    }
#pragma unroll
    for (int i = 0; i < 16; ++i) {
      int idx = tid + i * 256; hk_s[(idx >> 7) * 129 + (idx & 127)] = pf_hk[i];
    }
    __syncthreads();

    if (ch < 7) {  // prefetch next chunk under compute
      int c1 = (ch + 1) * 128;
#pragma unroll
      for (int i = 0; i < 4; ++i) {
        int idx = tid + i * 256; int r = idx >> 7, d = idx & 127;
        pf_hq[i] = hq[(b * 256 + q0 + r) * 1024 + c1 + d];
      }
#pragma unroll
      for (int i = 0; i < 16; ++i) {
        int idx = tid + i * 256; int r = idx >> 7, d = idx & 127;
        pf_hk[i] = hk[(b * 256 + k0 + r) * 1024 + c1 + d];
      }
    }

    const float* hkp = hk_s + kl * 129;
    const float* hqp = hq_s + qs * 129;
    const float* vap = vam2_s + ch * 128;
    float a0 = 0.f, a1 = 0.f, a2 = 0.f, a3 = 0.f;
#pragma unroll 4
    for (int d = 0; d < 128; d += 4) {
      float e0 = __builtin_amdgcn_exp2f(hqp[d + 0] + hkp[d + 0]);
      float e1 = __builtin_amdgcn_exp2f(hqp[d + 1] + hkp[d + 1]);
      float e2 = __builtin_amdgcn_exp2f(hqp[d + 2] + hkp[d + 2]);
      float e3 = __builtin_amdgcn_exp2f(hqp[d + 3] + hkp[d + 3]);
      a0 += vap[d + 0] * __builtin_amdgcn_rcpf(e0 + 1.0f);
      a1 += vap[d + 1] * __builtin_amdgcn_rcpf(e1 + 1.0f);
      a2 += vap[d + 2] * __builtin_amdgcn_rcpf(e2 + 1.0f);
      a3 += vap[d + 3] * __builtin_amdgcn_rcpf(e3 + 1.0f);
    }
    float logit = Ssum[ch] + ((a0 + a1) + (a2 + a3)) - pen;
    logits[((b * 8 + ch) * 256 + q0 + qs) * 256 + k0 + kl] = logit;
  }
}

// ---------------- Phase 2: softmax (in place) + PV ----------------
// grid: x = q-tile (32, TQ=8), y = h, z = b
__global__ __launch_bounds__(256) void softmax_pv(
    const float* __restrict__ values,
    float* __restrict__ weights,   // in: logits (penalty baked), out: softmax weights
    float* __restrict__ ctx)       // [B,Q,1024]
{
  __shared__ __align__(16) float w_lds[8 * 256];
  const int tid = threadIdx.x;
  const int b = blockIdx.z, h = blockIdx.y, q0 = blockIdx.x * 8;
  const int wave = tid >> 6, lane = tid & 63;

#pragma unroll
  for (int r = 0; r < 2; ++r) {
    const int row = wave * 2 + r;     // 0..7
    float* lp = &weights[((b * 8 + h) * 256 + q0 + row) * 256];
    float4 L = *(const float4*)&lp[lane * 4];
    float m = fmaxf(fmaxf(L.x, L.y), fmaxf(L.z, L.w));
#pragma unroll
    for (int off = 32; off; off >>= 1) m = fmaxf(m, __shfl_xor(m, off, 64));
    float4 P;
    P.x = __builtin_amdgcn_exp2f((L.x - m) * LOG2E);
    P.y = __builtin_amdgcn_exp2f((L.y - m) * LOG2E);
    P.z = __builtin_amdgcn_exp2f((L.z - m) * LOG2E);
    P.w = __builtin_amdgcn_exp2f((L.w - m) * LOG2E);
    float s = (P.x + P.y) + (P.z + P.w);
#pragma unroll
    for (int off = 32; off; off >>= 1) s += __shfl_xor(s, off, 64);
    float inv = 1.0f / s;   // accurate division
    P.x *= inv; P.y *= inv; P.z *= inv; P.w *= inv;
    *(float4*)&w_lds[row * 256 + lane * 4] = P;
    *(float4*)&lp[lane * 4] = P;
  }
  __syncthreads();

  // PV: thread -> (q = tid>>5, d4 = (tid&31)*4); loop k, coalesced float4 V loads
  const int q = tid >> 5, dq = tid & 31;
  const float* vb = values + (b * 256) * 1024 + h * 128 + dq * 4;
  const float* wrow = w_lds + q * 256;
  float4 accE = make_float4(0, 0, 0, 0), accO = make_float4(0, 0, 0, 0);
#pragma unroll 4
  for (int k = 0; k < 256; k += 2) {
    float4 v0 = *(const float4*)&vb[k * 1024];
    float4 v1 = *(const float4*)&vb[(k + 1) * 1024];
    float w0 = wrow[k], w1 = wrow[k + 1];
    accE.x += w0 * v0.x; accE.y += w0 * v0.y; accE.z += w0 * v0.z; accE.w += w0 * v0.w;
    accO.x += w1 * v1.x; accO.y += w1 * v1.y; accO.z += w1 * v1.z; accO.w += w1 * v1.w;
  }
  float4 o;
  o.x = accE.x + accO.x; o.y = accE.y + accO.y; o.z = accE.z + accO.z; o.w = accE.w + accO.w;
  *(float4*)&ctx[(b * 256 + q0 + q) * 1024 + h * 128 + dq * 4] = o;
}

extern "C" void kernel_launch(void* const* d_in, const int* in_sizes, int n_in,
                              void* d_out, int out_size, void* d_ws, size_t ws_size,
                              hipStream_t stream) {
  const float* query  = (const float*)d_in[0];
  const float* keys   = (const float*)d_in[1];
  const float* values = (const float*)d_in[2];
  const int*   mask   = (const int*)d_in[3];
  const float* Wq     = (const float*)d_in[4];
  const float* Wk     = (const float*)d_in[5];
  const float* Va     = (const float*)d_in[6];

  float* ctx     = (float*)d_out;            // [2,256,1024] = 524288 floats
  float* weights = ctx + 524288;             // [2,8,256,256] = 1048576 floats
  float* hq = (float*)d_ws;                  // 524288 floats (scaled projections)
  float* hk = hq + 524288;                   // 524288 floats

  gemm2_f32<<<dim3(16, 8, 2), 256, 0, stream>>>(query, keys, Wq, Wk, hq, hk);
  logits_kernel<<<dim3(8, 32, 2), 256, 0, stream>>>(hq, hk, Va, mask, weights);
  softmax_pv<<<dim3(32, 8, 2), 256, 0, stream>>>(values, weights, ctx);
}

// Round 2
// 110.565 us; speedup vs baseline: 1.0819x; 1.0819x over previous
//
#include <hip/hip_runtime.h>
#include <hip/hip_bf16.h>

// MultiHeadAttention (additive/Bahdanau): B=2, Q=K=256, HIDDEN=1024, 8 heads x 128
// Phase 0: hq' = (query@W_q)*2log2e, hk' = (keys@W_k)*2log2e  (fp32 partials, K-split, to d_ws)
// Phase 1: logits[b,h,q,k] = S_h + sum_d (-2*Va_d)/(2^(hq'+hk')+1) - penalty (to d_out weights region)
//          (partials summed during LDS staging; 2 heads per block for occupancy)
// Phase 2: softmax rows in place -> weights; PV -> ctx
//
// tanh(x) = 1 - 2/(e^{2x}+1); with a = 2*log2e*x: e^{2x} = 2^a. Handles +-inf saturation correctly.

#define TANH_SCALE 2.88539008177792681472f   // 2*log2(e)
#define LOG2E      1.44269504088896340736f

// ---------------- Phase 0: fp32 GEMM, partial C = scale * A[512,Kslice] @ W[Kslice,1024] ----------------
// grid.z: bit0 = {query,keys}, bits>=1 = K-split index. parts layout: [ks*2+zq][512*1024]
__global__ __launch_bounds__(256) void gemm2_f32(
    const float* __restrict__ query, const float* __restrict__ keys,
    const float* __restrict__ Wq, const float* __restrict__ Wk,
    float* __restrict__ parts, int ksplit)
{
  const int z = blockIdx.z;
  const int zq = z & 1, ks = z >> 1;
  const float* A = zq ? keys : query;
  const float* W = zq ? Wk : Wq;
  float* out = parts + (size_t)(ks * 2 + zq) * 524288;
  const int klen = 1024 / ksplit;
  const int kbeg = ks * klen, kend = kbeg + klen;

  __shared__ __align__(16) float As[16 * 68];  // [k][m], stride 68 (conflict-free, 16B-aligned rows)
  __shared__ __align__(16) float Ws[16 * 64];  // [k][n]

  const int tid = threadIdx.x;
  const int tx = tid & 15, ty = tid >> 4;
  const int m0 = blockIdx.y * 64, n0 = blockIdx.x * 64;

  const int ak = tid & 15, am = tid >> 4;   // A tile 64m x 16k
  const int wn = tid & 63, wk = tid >> 6;   // W tile 16k x 64n

  float ar[4], wr[4];
#pragma unroll
  for (int i = 0; i < 4; ++i) ar[i] = A[(m0 + am + i * 16) * 1024 + kbeg + ak];
#pragma unroll
  for (int i = 0; i < 4; ++i) wr[i] = W[(kbeg + wk + i * 4) * 1024 + n0 + wn];

  float acc[4][4] = {};

  for (int kk = kbeg; kk < kend; kk += 16) {
    __syncthreads();
#pragma unroll
    for (int i = 0; i < 4; ++i) As[ak * 68 + am + i * 16] = ar[i];
#pragma unroll
    for (int i = 0; i < 4; ++i) Ws[(wk + i * 4) * 64 + wn] = wr[i];
    __syncthreads();

    if (kk + 16 < kend) {  // prefetch next tile into registers
#pragma unroll
      for (int i = 0; i < 4; ++i) ar[i] = A[(m0 + am + i * 16) * 1024 + kk + 16 + ak];
#pragma unroll
      for (int i = 0; i < 4; ++i) wr[i] = W[(kk + 16 + wk + i * 4) * 1024 + n0 + wn];
    }

#pragma unroll
    for (int k = 0; k < 16; ++k) {
      float4 af = *(const float4*)&As[k * 68 + ty * 4];
      float4 wf = *(const float4*)&Ws[k * 64 + tx * 4];
      float a[4] = {af.x, af.y, af.z, af.w};
      float w[4] = {wf.x, wf.y, wf.z, wf.w};
#pragma unroll
      for (int i = 0; i < 4; ++i)
#pragma unroll
        for (int j = 0; j < 4; ++j) acc[i][j] += a[i] * w[j];
    }
  }

#pragma unroll
  for (int i = 0; i < 4; ++i) {
    float4 o;
    o.x = acc[i][0] * TANH_SCALE; o.y = acc[i][1] * TANH_SCALE;
    o.z = acc[i][2] * TANH_SCALE; o.w = acc[i][3] * TANH_SCALE;
    *(float4*)&out[(m0 + ty * 4 + i) * 1024 + n0 + tx * 4] = o;
  }
}

// ---------------- Phase 1: logits ----------------
// grid: x = k-tile (8, TK=32), y = q-tile (32, TQ=8), z = b + 2*headgroup (2 heads per block)
__global__ __launch_bounds__(256) void logits_kernel(
    const float* __restrict__ parts,
    const float* __restrict__ Va, const int* __restrict__ mask,
    float* __restrict__ logits /* [B,8,Q,K] */, int nparts)
{
  __shared__ float hk_s[32 * 129];   // stride 129: bank = (k+d)%32, conflict-free
  __shared__ float hq_s[8 * 129];
  __shared__ float vam2_s[256];      // -2*Va for the 2 owned heads
  __shared__ float Ssum[2];          // per-head sum(Va)

  const int tid = threadIdx.x;
  const int b  = blockIdx.z & 1;
  const int h0 = (blockIdx.z >> 1) * 2;       // first of 2 heads
  const int q0 = blockIdx.y * 8, k0 = blockIdx.x * 32;

  const float* pq0 = parts;
  const float* pk0 = parts + 524288;
  const float* pq1 = parts + 1048576;
  const float* pk1 = parts + 1572864;
  const bool np2 = (nparts == 2);

  vam2_s[tid] = -2.0f * Va[h0 * 128 + tid];
  __syncthreads();
  if (tid < 2) {
    float s = 0.f;
    for (int d = 0; d < 128; ++d) s += vam2_s[tid * 128 + d];
    Ssum[tid] = -0.5f * s;   // = sum(Va) over head
  }

  const int kl = tid & 31;   // key within tile
  const int qs = tid >> 5;   // query within tile (0..7)
  const float pen = 99.0f * (1.0f - (float)mask[b * 256 + k0 + kl]);

  float pf_hq[4], pf_hk[16];
  // prefetch chunk (head) h0
#pragma unroll
  for (int i = 0; i < 4; ++i) {
    int idx = tid + i * 256; int r = idx >> 7, d = idx & 127;
    size_t o = (size_t)(b * 256 + q0 + r) * 1024 + h0 * 128 + d;
    float v = pq0[o]; if (np2) v += pq1[o];
    pf_hq[i] = v;
  }
#pragma unroll
  for (int i = 0; i < 16; ++i) {
    int idx = tid + i * 256; int r = idx >> 7, d = idx & 127;
    size_t o = (size_t)(b * 256 + k0 + r) * 1024 + h0 * 128 + d;
    float v = pk0[o]; if (np2) v += pk1[o];
    pf_hk[i] = v;
  }

  for (int c = 0; c < 2; ++c) {   // one head (128 d) per chunk
    const int head = h0 + c;
    __syncthreads();
#pragma unroll
    for (int i = 0; i < 4; ++i) {
      int idx = tid + i * 256; hq_s[(idx >> 7) * 129 + (idx & 127)] = pf_hq[i];
    }
#pragma unroll
    for (int i = 0; i < 16; ++i) {
      int idx = tid + i * 256; hk_s[(idx >> 7) * 129 + (idx & 127)] = pf_hk[i];
    }
    __syncthreads();

    if (c < 1) {  // prefetch next head under compute
      int c1 = (head + 1) * 128;
#pragma unroll
      for (int i = 0; i < 4; ++i) {
        int idx = tid + i * 256; int r = idx >> 7, d = idx & 127;
        size_t o = (size_t)(b * 256 + q0 + r) * 1024 + c1 + d;
        float v = pq0[o]; if (np2) v += pq1[o];
        pf_hq[i] = v;
      }
#pragma unroll
      for (int i = 0; i < 16; ++i) {
        int idx = tid + i * 256; int r = idx >> 7, d = idx & 127;
        size_t o = (size_t)(b * 256 + k0 + r) * 1024 + c1 + d;
        float v = pk0[o]; if (np2) v += pk1[o];
        pf_hk[i] = v;
      }
    }

    const float* hkp = hk_s + kl * 129;
    const float* hqp = hq_s + qs * 129;
    const float* vap = vam2_s + c * 128;
    float a0 = 0.f, a1 = 0.f, a2 = 0.f, a3 = 0.f;
#pragma unroll 4
    for (int d = 0; d < 128; d += 4) {
      float e0 = __builtin_amdgcn_exp2f(hqp[d + 0] + hkp[d + 0]);
      float e1 = __builtin_amdgcn_exp2f(hqp[d + 1] + hkp[d + 1]);
      float e2 = __builtin_amdgcn_exp2f(hqp[d + 2] + hkp[d + 2]);
      float e3 = __builtin_amdgcn_exp2f(hqp[d + 3] + hkp[d + 3]);
      a0 += vap[d + 0] * __builtin_amdgcn_rcpf(e0 + 1.0f);
      a1 += vap[d + 1] * __builtin_amdgcn_rcpf(e1 + 1.0f);
      a2 += vap[d + 2] * __builtin_amdgcn_rcpf(e2 + 1.0f);
      a3 += vap[d + 3] * __builtin_amdgcn_rcpf(e3 + 1.0f);
    }
    float logit = Ssum[c] + ((a0 + a1) + (a2 + a3)) - pen;
    logits[((size_t)(b * 8 + head) * 256 + q0 + qs) * 256 + k0 + kl] = logit;
  }
}

// ---------------- Phase 2: softmax (in place) + PV ----------------
// grid: x = q-tile (32, TQ=8), y = h, z = b
__global__ __launch_bounds__(256) void softmax_pv(
    const float* __restrict__ values,
    float* __restrict__ weights,   // in: logits (penalty baked), out: softmax weights
    float* __restrict__ ctx)       // [B,Q,1024]
{
  __shared__ __align__(16) float w_lds[8 * 256];
  const int tid = threadIdx.x;
  const int b = blockIdx.z, h = blockIdx.y, q0 = blockIdx.x * 8;
  const int wave = tid >> 6, lane = tid & 63;

#pragma unroll
  for (int r = 0; r < 2; ++r) {
    const int row = wave * 2 + r;     // 0..7
    float* lp = &weights[((size_t)(b * 8 + h) * 256 + q0 + row) * 256];
    float4 L = *(const float4*)&lp[lane * 4];
    float m = fmaxf(fmaxf(L.x, L.y), fmaxf(L.z, L.w));
#pragma unroll
    for (int off = 32; off; off >>= 1) m = fmaxf(m, __shfl_xor(m, off, 64));
    float4 P;
    P.x = __builtin_amdgcn_exp2f((L.x - m) * LOG2E);
    P.y = __builtin_amdgcn_exp2f((L.y - m) * LOG2E);
    P.z = __builtin_amdgcn_exp2f((L.z - m) * LOG2E);
    P.w = __builtin_amdgcn_exp2f((L.w - m) * LOG2E);
    float s = (P.x + P.y) + (P.z + P.w);
#pragma unroll
    for (int off = 32; off; off >>= 1) s += __shfl_xor(s, off, 64);
    float inv = 1.0f / s;   // accurate division
    P.x *= inv; P.y *= inv; P.z *= inv; P.w *= inv;
    *(float4*)&w_lds[row * 256 + lane * 4] = P;
    *(float4*)&lp[lane * 4] = P;
  }
  __syncthreads();

  // PV: thread -> (q = tid>>5, d4 = (tid&31)*4); loop k, coalesced float4 V loads
  const int q = tid >> 5, dq = tid & 31;
  const float* vb = values + (size_t)(b * 256) * 1024 + h * 128 + dq * 4;
  const float* wrow = w_lds + q * 256;
  float4 accE = make_float4(0, 0, 0, 0), accO = make_float4(0, 0, 0, 0);
#pragma unroll 4
  for (int k = 0; k < 256; k += 2) {
    float4 v0 = *(const float4*)&vb[k * 1024];
    float4 v1 = *(const float4*)&vb[(k + 1) * 1024];
    float w0 = wrow[k], w1 = wrow[k + 1];
    accE.x += w0 * v0.x; accE.y += w0 * v0.y; accE.z += w0 * v0.z; accE.w += w0 * v0.w;
    accO.x += w1 * v1.x; accO.y += w1 * v1.y; accO.z += w1 * v1.z; accO.w += w1 * v1.w;
  }
  float4 o;
  o.x = accE.x + accO.x; o.y = accE.y + accO.y; o.z = accE.z + accO.z; o.w = accE.w + accO.w;
  *(float4*)&ctx[(size_t)(b * 256 + q0 + q) * 1024 + h * 128 + dq * 4] = o;
}

extern "C" void kernel_launch(void* const* d_in, const int* in_sizes, int n_in,
                              void* d_out, int out_size, void* d_ws, size_t ws_size,
                              hipStream_t stream) {
  const float* query  = (const float*)d_in[0];
  const float* keys   = (const float*)d_in[1];
  const float* values = (const float*)d_in[2];
  const int*   mask   = (const int*)d_in[3];
  const float* Wq     = (const float*)d_in[4];
  const float* Wk     = (const float*)d_in[5];
  const float* Va     = (const float*)d_in[6];

  float* ctx     = (float*)d_out;            // [2,256,1024] = 524288 floats
  float* weights = ctx + 524288;             // [2,8,256,256] = 1048576 floats
  float* parts   = (float*)d_ws;             // up to 4 x 524288 floats (K-split partials)

  const int ksplit = (ws_size >= (size_t)8 * 1024 * 1024) ? 2 : 1;

  gemm2_f32<<<dim3(16, 8, 2 * ksplit), 256, 0, stream>>>(query, keys, Wq, Wk, parts, ksplit);
  logits_kernel<<<dim3(8, 32, 8), 256, 0, stream>>>(parts, Va, mask, weights, ksplit);
  softmax_pv<<<dim3(32, 8, 2), 256, 0, stream>>>(values, weights, ctx);
}